// Round 12
// baseline (1211.113 us; speedup 1.0000x reference)
//
#include <hip/hip_runtime.h>
#include <stdint.h>

#define T_STEPS 14
#define B_DIM   4096
#define I_DIM   2048
#define H_DIM   1024
#define O_DIM   128
#define K_TOT   3072   // I_DIM + H_DIM
#define ZBYTES  ((size_t)B_DIM * H_DIM)

// fixed-point scale 2^25: |w|max ~0.16 -> |W| ~5.1M, 3 signed base-256 digits exact
#define WSCALE_F 33554432.0f

typedef __bf16  bf16x8  __attribute__((ext_vector_type(8)));
typedef float   floatx4 __attribute__((ext_vector_type(4)));
typedef int     int4v   __attribute__((ext_vector_type(4)));
typedef int     int16v  __attribute__((ext_vector_type(16)));
typedef unsigned long long u64;

__device__ __forceinline__ uint16_t f2bf_rne(float f) {
    uint32_t u = __float_as_uint(f);
    u += 0x7fffu + ((u >> 16) & 1u);
    return (uint16_t)(u >> 16);
}
__device__ __forceinline__ float bf2f(uint16_t h) {
    return __uint_as_float(((uint32_t)h) << 16);
}

// async global->LDS, 16B/lane; LDS dest = wave-uniform base + lane*16 (implicit)
__device__ __forceinline__ void gload_lds16(const void* g, void* l) {
    __builtin_amdgcn_global_load_lds((__attribute__((address_space(1))) void*)g,
                                     (__attribute__((address_space(3))) void*)l, 16, 0, 0);
}

// ================= fragment-order layouts, BK=128 (validated r11) =================
// B digits: WB[nt(32)][ktw(24)][s(3)][kk(4)][lane(64)][16B]      (12 KB chunks)
// A spikes: Xall[t][mIdx(32)][ktx(16)][group(4)][kk(4)][lane(64)][16B]  (16 KB chunks)
// Z state:  ZS[t][mIdx(32)][ktz(8)][group(4)][kk(4)][lane(64)][16B]     (16 KB chunks)
// element (row = group*32 + (lane&31), k = kt*128 + kk*32 + (lane>>5)*16 + j)

__global__ void split_w_kernel(const float* __restrict__ w_in, const float* __restrict__ w_rec,
                               int8_t* __restrict__ WB) {
    int idx = blockIdx.x * 256 + threadIdx.x;          // over H_DIM*K_TOT
    int h = idx / K_TOT;
    int k = idx - h * K_TOT;
    float w = (k < I_DIM) ? w_in[(size_t)h * I_DIM + k]
                          : w_rec[(size_t)h * H_DIM + (k - I_DIM)];
    int W  = __float2int_rn(w * WSCALE_F);
    int d0 = (int8_t)(W & 0xFF);
    int r1 = (W - d0) >> 8;
    int d1 = (int8_t)(r1 & 0xFF);
    int d2 = (r1 - d1) >> 8;                           // |d2| <= ~80
    int nt = h >> 5, n32 = h & 31;
    int ktw = k >> 7, k128 = k & 127;
    int kk = k128 >> 5, half = (k128 >> 4) & 1, j = k128 & 15;
    int lane = half * 32 + n32;
    size_t base = (size_t)(nt * 24 + ktw) * 12288 + kk * 1024 + lane * 16 + j;
    WB[base] = (int8_t)d0; WB[base + 4096] = (int8_t)d1; WB[base + 8192] = (int8_t)d2;
}

// ---------- out_w -> bf16 hi/mid/lo (validated) ----------
__global__ void split_ow_kernel(const float* __restrict__ out_w, uint16_t* __restrict__ OW3) {
    int idx = blockIdx.x * 256 + threadIdx.x;          // over O_DIM*H_DIM
    float w = out_w[idx];
    uint16_t hi = f2bf_rne(w);
    float r1 = w - bf2f(hi);
    uint16_t mid = f2bf_rne(r1);
    float r2 = r1 - bf2f(mid);
    uint16_t lo = f2bf_rne(r2);
    const size_t S = (size_t)O_DIM * H_DIM;
    OW3[idx] = hi; OW3[idx + S] = mid; OW3[idx + 2 * S] = lo;
}

// ---------- x fp32 -> i8, R12 rewrite: BOTH sides coalesced via LDS transpose ----------
// R11 post-mortem: old cvt_x's wave-instructions read 64B from 32 rows 8KB apart
// (DRAM-row hostile; est. ~250-350us of the stable ~585us non-persist time).
// New: one 256-thread block per 16KB output chunk (t,mIdx,kt).
//  read : per wave-instruction, lanes 0..31 = row r bytes contiguous (512B), lanes
//         32..63 = row r+1 -> fully coalesced fp32 reads.
//  LDS  : 4B packed spike bytes scattered to fragment-order position (<=8-way alias,
//         trivial volume).
//  write: thread tid stores 64B contiguous -> fully coalesced.
// Output bit-identical to the validated layout:
//   byte(b=mIdx*128+group*32+row32, k=kt*128+kk*32+half*16+j)
//     at chunkBase + group*4096 + kk*1024 + (half*32+row32)*16 + j
__global__ void cvt_x_kernel(const float* __restrict__ x, int8_t* __restrict__ xb) {
    __shared__ int8_t sL[16384];
    const int chunk = blockIdx.x;                 // (t*32 + mIdx)*16 + kt
    const int kt   = chunk & 15;
    const int mIdx = (chunk >> 4) & 31;
    const int t    = chunk >> 9;
    const int tid  = threadIdx.x;
    const int wave = tid >> 6, lane = tid & 63;
    const int l31  = lane & 31;
    const int kk   = l31 >> 3, half = (l31 >> 2) & 1, j4 = (l31 & 3) * 4;
    const float* xrowbase = x + ((size_t)t * B_DIM + mIdx * 128) * I_DIM + kt * 128 + l31 * 4;
#pragma unroll
    for (int it = 0; it < 16; ++it) {
        const int r = wave * 32 + it * 2 + (lane >> 5);     // 0..127
        const int group = r >> 5, row32 = r & 31;
        float4 f = *(const float4*)(xrowbase + (size_t)r * I_DIM);
        uint32_t p = (uint32_t)(f.x > 0.5f)
                   | ((uint32_t)(f.y > 0.5f) << 8)
                   | ((uint32_t)(f.z > 0.5f) << 16)
                   | ((uint32_t)(f.w > 0.5f) << 24);
        *(uint32_t*)&sL[group * 4096 + kk * 1024 + (half * 32 + row32) * 16 + j4] = p;
    }
    __syncthreads();
    int4v* dst = (int4v*)xb + (size_t)chunk * 1024 + tid * 4;
    const int4v* srcv = (const int4v*)sL + tid * 4;
#pragma unroll
    for (int w = 0; w < 4; ++w) dst[w] = srcv[w];
}

// ---------- zero the group-sync counters ----------
__global__ void zero_cnt_kernel(uint32_t* __restrict__ cnt) {
    __hip_atomic_store(&cnt[blockIdx.x * 256 + threadIdx.x], 0u,
                       __ATOMIC_RELAXED, __HIP_MEMORY_SCOPE_AGENT);
}

// ====== R11 persist machinery (validated; UNCHANGED this round) ======
// 64Mx32N waves, 128Mx64N tile, full-iteration LDS staging, vmcnt(10) ping-pong.
__device__ __forceinline__ void stage_a(const int8_t* __restrict__ aC, int8_t* dst,
                                        int wave, int lane) {
#pragma unroll
    for (int j = 0; j < 4; ++j) {
        const int seg = j * 4 + wave;
        gload_lds16(aC + (size_t)seg * 1024 + lane * 16, dst + seg * 1024);
    }
}
__device__ __forceinline__ void stage_b(const int8_t* __restrict__ bA,
                                        const int8_t* __restrict__ bB,
                                        int8_t* dst, int wave, int lane) {
    gload_lds16(bA + (size_t)wave * 1024 + lane * 16,       dst + wave * 1024);
    gload_lds16(bA + (size_t)(4 + wave) * 1024 + lane * 16, dst + (4 + wave) * 1024);
    gload_lds16(bA + (size_t)(8 + wave) * 1024 + lane * 16, dst + (8 + wave) * 1024);
    gload_lds16(bB + (size_t)wave * 1024 + lane * 16,       dst + 12288 + wave * 1024);
    gload_lds16(bB + (size_t)(4 + wave) * 1024 + lane * 16, dst + 12288 + (4 + wave) * 1024);
    gload_lds16(bB + (size_t)(8 + wave) * 1024 + lane * 16, dst + 12288 + (8 + wave) * 1024);
}

__device__ __forceinline__ void lif_iter(const int8_t* __restrict__ aCn,   // A(kt+1) chunk or null
                                         const int8_t* __restrict__ bAn,   // B(kt+1) strip0 or null
                                         const int8_t* __restrict__ bBn,   // B(kt+1) strip1 or null
                                         const int8_t* curA, const int8_t* curB,
                                         int8_t* nxtA, int8_t* nxtB,
                                         int wave, int lane, bool stage_next,
                                         int16v (&acc)[2][3]) {
    if (stage_next) {
        stage_a(aCn, nxtA, wave, lane);
        stage_b(bAn, bBn, nxtB, wave, lane);
        __builtin_amdgcn_sched_barrier(0);
        asm volatile("s_waitcnt vmcnt(10)" ::: "memory");  // drain A(kt)+B(kt) stages; keep kt+1's 10
    } else {
        asm volatile("s_waitcnt vmcnt(0)" ::: "memory");   // tail: drain everything
    }
    __builtin_amdgcn_s_barrier();                          // all waves' A(kt)/B(kt) landed
    __builtin_amdgcn_sched_barrier(0);
    // wave (p = wave>>1, n = wave&1) owns rows [p*64, p*64+64) x strip n.
    // A-frag groups g = 2p+mf = (wave&~1)+mf; each bF feeds both mf MFMAs.
    const int gbase = wave & ~1;
    const int n = wave & 1;
    __builtin_amdgcn_s_setprio(1);                         // T5: favor MFMA-entering wave
#pragma unroll
    for (int kk = 0; kk < 4; ++kk) {
        int4v aF0 = *(const int4v*)(curA + gbase * 4096 + kk * 1024 + lane * 16);
        int4v aF1 = *(const int4v*)(curA + (gbase + 1) * 4096 + kk * 1024 + lane * 16);
#pragma unroll
        for (int s = 0; s < 3; ++s) {
            int4v bF = *(const int4v*)(curB + n * 12288 + s * 4096 + kk * 1024 + lane * 16);
            acc[0][s] = __builtin_amdgcn_mfma_i32_32x32x32_i8(aF0, bF, acc[0][s], 0, 0, 0);
            acc[1][s] = __builtin_amdgcn_mfma_i32_32x32x32_i8(aF1, bF, acc[1][s], 0, 0, 0);
        }
    }
    __builtin_amdgcn_s_setprio(0);
    asm volatile("s_waitcnt lgkmcnt(0)" ::: "memory");     // reads of cur done
    __builtin_amdgcn_s_barrier();                          // safe to overwrite cur next iter
}

// Contract: caller has ISSUED A(0)->sA0 and B(0)->sB0 (first iter's vmcnt(10) or an
// intervening __syncthreads completes them). NKT even: phase starts at buf0, last
// compute uses buf1, leaves buf0 free for the next phase's prologue.
template<int NKT>
__device__ __forceinline__ void run_phase(const int8_t* __restrict__ aC,   // A chunk base, +kt*16384
                                          const int8_t* __restrict__ bA,   // strip0 base, +kt*12288
                                          const int8_t* __restrict__ bB,   // strip1 base, +kt*12288
                                          int8_t* sA0, int8_t* sA1, int8_t* sB0, int8_t* sB1,
                                          int wave, int lane, int16v (&acc)[2][3]) {
#pragma unroll 1
    for (int kt = 0; kt + 2 < NKT; kt += 2) {
        lif_iter(aC + (size_t)(kt + 1) * 16384, bA + (size_t)(kt + 1) * 12288,
                 bB + (size_t)(kt + 1) * 12288, sA0, sB0, sA1, sB1, wave, lane, true, acc);
        lif_iter(aC + (size_t)(kt + 2) * 16384, bA + (size_t)(kt + 2) * 12288,
                 bB + (size_t)(kt + 2) * 12288, sA1, sB1, sA0, sB0, wave, lane, true, acc);
    }
    lif_iter(aC + (size_t)(NKT - 1) * 16384, bA + (size_t)(NKT - 1) * 12288,
             bB + (size_t)(NKT - 1) * 12288, sA0, sB0, sA1, sB1, wave, lane, true, acc);
    lif_iter(nullptr, nullptr, nullptr, sA1, sB1, sA0, sB0, wave, lane, false, acc);
}

// ================= persistent LIF: all 14 steps, ONE PLAIN launch =================
// Tile 128M x 64N, grid 512, 2 blocks/CU: LDS 80KB x2 = 160KB exact, VGPR <= 256
// (launch_bounds 256,2 -> 8 waves/CU). mIdx group = 16 blocks (flag target 16).
// XCD grouping: mIdx = (bid&7)*4 + (q&3), nt2 = q>>2.
// Coherence protocol — validated R6/R8/R9/R10/R11 through the timed path (no fences):
//  - dispatch boundaries invalidate L2s (replay staleness handled);
//  - ZS[t] virgin until producers' agent-scope 8B stores (LLC write-through,
//    vmcnt-acked before flag add); consumers spin + __syncthreads -> cached loads fresh;
//  - flag spin: relaxed agent-scope loads (no invalidates, groups drift freely).
__launch_bounds__(256, 2)
__global__ void lif_persist_kernel(const int8_t* __restrict__ Xall,
                                   const int8_t* __restrict__ WB,
                                   int8_t* __restrict__ ZS,      // 13 per-step z buffers
                                   uint16_t* __restrict__ Zbf,
                                   uint32_t* __restrict__ cnt) {
    __shared__ int8_t sMem[81920];
    int8_t* const sA0 = sMem;               // 16 KB
    int8_t* const sA1 = sMem + 16384;       // 16 KB (sZ aliases here during epilogue)
    int8_t* const sB0 = sMem + 32768;       // 24 KB
    int8_t* const sB1 = sMem + 57344;       // 24 KB
    int8_t* const sZ  = sA1;                // dead at epilogue time (ordering audited)

    const int tid  = threadIdx.x;
    const int wave = tid >> 6, lane = tid & 63;
    const int lane32 = lane & 31, hl = lane >> 5;

    // group-per-XCD swizzle: 512 blocks, 64 per XCD = 4 mIdx x 16 nt2
    const int bid = blockIdx.x;
    const int xs = bid & 7, q = bid >> 3;       // q in 0..63
    const int mIdx = xs * 4 + (q & 3);
    const int nt2  = q >> 2;                    // 0..15, covers nt = 2*nt2, 2*nt2+1

    const int mBase = mIdx * 128, nBase = nt2 * 64;
    const int8_t* wbA = WB + (size_t)(2 * nt2) * 24 * 12288;
    const int8_t* wbB = WB + (size_t)(2 * nt2 + 1) * 24 * 12288;

    // wave partition: p = row-half (64 rows), n = strip
    const int p = wave >> 1, n = wave & 1;

    float vmem[2][16], isyn[2][16];
#pragma unroll
    for (int mf = 0; mf < 2; ++mf)
#pragma unroll
        for (int r = 0; r < 16; ++r) { vmem[mf][r] = 0.0f; isyn[mf][r] = 0.0f; }

    // initial prologue: X(t=0) A(0) + B(0) -> buf0 (first iter's vmcnt(10) drains)
    stage_a(Xall + (size_t)mIdx * 16 * 16384, sA0, wave, lane);
    stage_b(wbA, wbB, sB0, wave, lane);

    for (int t = 0; t < T_STEPS; ++t) {
        int16v acc[2][3] = {};   // [mf][digit]

        // ---- X phase: kt 0..15 (A(0)/B(0) already staged into buf0) ----
        const int8_t* XtC = Xall + (size_t)t * ((size_t)B_DIM * I_DIM)
                          + (size_t)mIdx * 16 * 16384;
        run_phase<16>(XtC, wbA, wbB, sA0, sA1, sB0, sB1, wave, lane, acc);

        // ---- recurrent phase: needs z(t-1) from the 16 blocks of this mIdx group ----
        if (t > 0) {
            const int8_t* zbA = wbA + (size_t)16 * 12288;
            const int8_t* zbB = wbB + (size_t)16 * 12288;
            stage_b(zbA, zbB, sB0, wave, lane);   // W independent of z: hide under spin
            if (tid == 0) {
                const uint32_t* f = cnt + ((size_t)mIdx * 13 + (t - 1)) * 32;
                while (__hip_atomic_load((uint32_t*)f, __ATOMIC_RELAXED, __HIP_MEMORY_SCOPE_AGENT) < 16u)
                    __builtin_amdgcn_s_sleep(2);
            }
            __syncthreads();   // spin visible; full barrier; drains B(0) stage
            const int8_t* zC = ZS + (size_t)(t - 1) * ZBYTES + (size_t)mIdx * 8 * 16384;
            stage_a(zC, sA0, wave, lane);         // z A(0); first iter's vmcnt(10) drains it
            run_phase<8>(zC, zbA, zbB, sA0, sA1, sB0, sB1, wave, lane, acc);
        }

        // ---- prestage NEXT step's X A(0)/B(0) into buf0 (free after even-NKT phase);
        //      latency hides under the epilogue; drained by epilogue __syncthreads ----
        if (t + 1 < T_STEPS) {
            stage_a(Xall + (size_t)(t + 1) * ((size_t)B_DIM * I_DIM)
                    + (size_t)mIdx * 16 * 16384, sA0, wave, lane);
            stage_b(wbA, wbB, sB0, wave, lane);
        }

        // ---- LIF epilogue (registers): C/D row=(r&3)+8*(r>>2)+4*hl, col=lane32 ----
#pragma unroll
        for (int mf = 0; mf < 2; ++mf) {
#pragma unroll
            for (int r = 0; r < 16; ++r) {
#pragma clang fp contract(off)
                // exact digit combine (|counts| < 2^24)
                float cur = (float)acc[mf][2][r] * (1.0f / 512.0f)
                          + (float)acc[mf][1][r] * (1.0f / 131072.0f)
                          + (float)acc[mf][0][r] * (1.0f / 33554432.0f);
                int row = (r & 3) + 8 * (r >> 2) + 4 * hl;    // 0..31 (C/D layout)
                float v_dec = vmem[mf][r] + 0.1f * ((0.0f - vmem[mf][r]) + isyn[mf][r]);
                float i_dec = isyn[mf][r] - 0.2f * isyn[mf][r];
                bool z = (v_dec > 1.0f);
                vmem[mf][r] = z ? 0.0f : v_dec;               // == (1-z)*v_dec + z*V_RESET exactly
                isyn[mf][r] = i_dec + cur;
                if (t == T_STEPS - 1) {
                    int b = mBase + p * 64 + mf * 32 + row;
                    int h = nBase + n * 32 + lane32;
                    Zbf[(size_t)b * H_DIM + h] = z ? (uint16_t)0x3F80 : (uint16_t)0;
                } else {
                    // sZ[strip][group=2p+mf][lane'*16+j] — same layout as R10
                    sZ[n * 4096 + ((wave & ~1) + mf) * 1024
                       + ((lane32 >> 4) * 32 + row) * 16 + (lane32 & 15)]
                        = z ? (int8_t)1 : (int8_t)0;
                }
            }
        }

        if (t < T_STEPS - 1) {
            __syncthreads();   // sZ complete; drains prestaged A/B (vmcnt 0)
            // repack: per strip, 16 contiguous bytes/thread -> two 8B agent-scope stores
#pragma unroll
            for (int ns = 0; ns < 2; ++ns) {
                const u64* sp = (const u64*)&sZ[ns * 4096 + tid * 16];
                u64 v0 = sp[0], v1 = sp[1];
                const int ntn = nt2 * 2 + ns;
                int8_t* dst = ZS + (size_t)t * ZBYTES + ((size_t)mIdx * 8 + (ntn >> 2)) * 16384
                            + (tid >> 6) * 4096 + (ntn & 3) * 1024 + (tid & 63) * 16;
                __hip_atomic_store((u64*)dst,       v0, __ATOMIC_RELAXED, __HIP_MEMORY_SCOPE_AGENT);
                __hip_atomic_store((u64*)(dst + 8), v1, __ATOMIC_RELAXED, __HIP_MEMORY_SCOPE_AGENT);
            }
            __syncthreads();   // all z-stores acked at the coherence point; sZ reads done
            if (tid == 0)
                __hip_atomic_fetch_add(&cnt[((size_t)mIdx * 13 + t) * 32], 1u,
                                       __ATOMIC_RELAXED, __HIP_MEMORY_SCOPE_AGENT);
        }
    }
}

// ---------- output GEMM: out = z_T @ out_w^T + out_b (bf16x3) ----------
__launch_bounds__(256)
__global__ void out_gemm_kernel(const uint16_t* __restrict__ Zfin,  // [B][H_DIM] bf16
                                const uint16_t* __restrict__ OW3,   // [3][O_DIM][H_DIM] bf16
                                const float* __restrict__ out_b,
                                float* __restrict__ out) {
    __shared__ uint16_t sA[16 * 32];        // 1 KB : [row(16)][k(32)]
    __shared__ uint16_t sB[3][128 * 32];    // 24 KB: [s][row(128)][k(32)]

    const int tid  = threadIdx.x;
    const int wave = tid >> 6, lane = tid & 63;
    const int quad = lane >> 4, col = lane & 15;

    const int mBase = blockIdx.x * 16;

    floatx4 acc[2] = {};

    const int ldRow = lane >> 2;        // 0..15
    const int ldCol = (lane & 3) * 8;   // element offset (x2B = 16B)

    for (int kt = 0; kt < H_DIM / 32; ++kt) {
        const int kb = kt * 32;
        __syncthreads();
        if (wave == 0) {
            const uint16_t* g = Zfin + (size_t)(mBase + ldRow) * H_DIM + kb + ldCol;
            gload_lds16(g, &sA[0]);
        }
#pragma unroll
        for (int s = 0; s < 3; ++s) {
            const uint16_t* wsrc = OW3 + (size_t)s * O_DIM * H_DIM;
#pragma unroll
            for (int j = 0; j < 2; ++j) {
                const int rseg = j * 4 + wave;   // 0..7, 16 rows each
                const uint16_t* g = wsrc + (size_t)(rseg * 16 + ldRow) * H_DIM + kb + ldCol;
                gload_lds16(g, &sB[s][rseg * 16 * 32]);
            }
        }
        __syncthreads();

        bf16x8 aF = *reinterpret_cast<const bf16x8*>(&sA[col * 32 + quad * 8]);
#pragma unroll
        for (int s = 0; s < 3; ++s) {
#pragma unroll
            for (int ni = 0; ni < 2; ++ni) {
                int row = wave * 32 + ni * 16 + col;
                bf16x8 bF = *reinterpret_cast<const bf16x8*>(&sB[s][row * 32 + quad * 8]);
                acc[ni] = __builtin_amdgcn_mfma_f32_16x16x32_bf16(aF, bF, acc[ni], 0, 0, 0);
            }
        }
    }

    {
#pragma clang fp contract(off)
#pragma unroll
        for (int ni = 0; ni < 2; ++ni)
#pragma unroll
            for (int r = 0; r < 4; ++r) {
                int b = mBase + quad * 4 + r;          // C/D: row = quad*4 + reg
                int h = wave * 32 + ni * 16 + col;     //      col = lane&15
                out[(size_t)b * O_DIM + h] = acc[ni][r] + out_b[h];
            }
    }
}

extern "C" void kernel_launch(void* const* d_in, const int* in_sizes, int n_in,
                              void* d_out, int out_size, void* d_ws, size_t ws_size,
                              hipStream_t stream) {
    const float* x     = (const float*)d_in[0];
    const float* w_in  = (const float*)d_in[1];
    const float* w_rec = (const float*)d_in[2];
    const float* out_w = (const float*)d_in[3];
    const float* out_b = (const float*)d_in[4];
    float* out = (float*)d_out;

    char* ws = (char*)d_ws;
    size_t off = 0;
    int8_t*   WB   = (int8_t*)(ws + off);   off += (size_t)3 * H_DIM * K_TOT;        // 9.4 MB
    uint16_t* OW3  = (uint16_t*)(ws + off); off += (size_t)3 * O_DIM * H_DIM * 2;    // 0.8 MB
    int8_t*   Xall = (int8_t*)(ws + off);   off += (size_t)T_STEPS * B_DIM * I_DIM;  // 117 MB
    uint16_t* Zbf  = (uint16_t*)(ws + off); off += (size_t)B_DIM * H_DIM * 2;        // 8 MB
    int8_t*   ZS   = (int8_t*)(ws + off);   off += (size_t)13 * ZBYTES;              // 54.5 MB (per-step z)
    uint32_t* CNT  = (uint32_t*)(ws + off); off += (size_t)32 * 13 * 32 * 4;         // 53 KB

    split_w_kernel<<<(H_DIM * K_TOT) / 256, 256, 0, stream>>>(w_in, w_rec, WB);
    split_ow_kernel<<<(O_DIM * H_DIM) / 256, 256, 0, stream>>>(out_w, OW3);
    cvt_x_kernel<<<T_STEPS * 32 * 16, 256, 0, stream>>>(x, Xall);
    zero_cnt_kernel<<<(32 * 13 * 32) / 256, 256, 0, stream>>>(CNT);

    // PLAIN launch: capture-safe. 512 blocks = 2/CU exact-fit (160KB LDS / 2 blocks).
    lif_persist_kernel<<<dim3(512), dim3(256), 0, stream>>>(Xall, WB, ZS, Zbf, CNT);

    out_gemm_kernel<<<B_DIM / 16, 256, 0, stream>>>(Zbf, OW3, out_b, out);
}

// Round 14
// 1198.083 us; speedup vs baseline: 1.0109x; 1.0109x over previous
//
#include <hip/hip_runtime.h>
#include <stdint.h>

#define T_STEPS 14
#define B_DIM   4096
#define I_DIM   2048
#define H_DIM   1024
#define O_DIM   128
#define K_TOT   3072   // I_DIM + H_DIM
#define ZBYTES  ((size_t)B_DIM * H_DIM)

// fixed-point scale 2^25: |w|max ~0.16 -> |W| ~5.1M, 3 signed base-256 digits exact
#define WSCALE_F 33554432.0f

typedef __bf16  bf16x8  __attribute__((ext_vector_type(8)));
typedef float   floatx4 __attribute__((ext_vector_type(4)));
typedef int     int4v   __attribute__((ext_vector_type(4)));
typedef int     int16v  __attribute__((ext_vector_type(16)));
typedef unsigned long long u64;

__device__ __forceinline__ uint16_t f2bf_rne(float f) {
    uint32_t u = __float_as_uint(f);
    u += 0x7fffu + ((u >> 16) & 1u);
    return (uint16_t)(u >> 16);
}
__device__ __forceinline__ float bf2f(uint16_t h) {
    return __uint_as_float(((uint32_t)h) << 16);
}

// async global->LDS, 16B/lane; LDS dest = wave-uniform base + lane*16 (implicit)
__device__ __forceinline__ void gload_lds16(const void* g, void* l) {
    __builtin_amdgcn_global_load_lds((__attribute__((address_space(1))) void*)g,
                                     (__attribute__((address_space(3))) void*)l, 16, 0, 0);
}

// ================= fragment-order layouts, BK=128 (validated r11) =================
// B digits: WB[nt(32)][ktw(24)][s(3)][kk(4)][lane(64)][16B]      (12 KB chunks)
// A spikes: Xall[t][mIdx(32)][ktx(16)][group(4)][kk(4)][lane(64)][16B]  (16 KB chunks)
// Z state:  ZS[t][mIdx(32)][ktz(8)][group(4)][kk(4)][lane(64)][16B]     (16 KB chunks)
// element (row = group*32 + (lane&31), k = kt*128 + kk*32 + (lane>>5)*16 + j)

__global__ void split_w_kernel(const float* __restrict__ w_in, const float* __restrict__ w_rec,
                               int8_t* __restrict__ WB) {
    int idx = blockIdx.x * 256 + threadIdx.x;          // over H_DIM*K_TOT
    int h = idx / K_TOT;
    int k = idx - h * K_TOT;
    float w = (k < I_DIM) ? w_in[(size_t)h * I_DIM + k]
                          : w_rec[(size_t)h * H_DIM + (k - I_DIM)];
    int W  = __float2int_rn(w * WSCALE_F);
    int d0 = (int8_t)(W & 0xFF);
    int r1 = (W - d0) >> 8;
    int d1 = (int8_t)(r1 & 0xFF);
    int d2 = (r1 - d1) >> 8;                           // |d2| <= ~80
    int nt = h >> 5, n32 = h & 31;
    int ktw = k >> 7, k128 = k & 127;
    int kk = k128 >> 5, half = (k128 >> 4) & 1, j = k128 & 15;
    int lane = half * 32 + n32;
    size_t base = (size_t)(nt * 24 + ktw) * 12288 + kk * 1024 + lane * 16 + j;
    WB[base] = (int8_t)d0; WB[base + 4096] = (int8_t)d1; WB[base + 8192] = (int8_t)d2;
}

// ---------- out_w -> bf16 hi/mid/lo (validated) ----------
__global__ void split_ow_kernel(const float* __restrict__ out_w, uint16_t* __restrict__ OW3) {
    int idx = blockIdx.x * 256 + threadIdx.x;          // over O_DIM*H_DIM
    float w = out_w[idx];
    uint16_t hi = f2bf_rne(w);
    float r1 = w - bf2f(hi);
    uint16_t mid = f2bf_rne(r1);
    float r2 = r1 - bf2f(mid);
    uint16_t lo = f2bf_rne(r2);
    const size_t S = (size_t)O_DIM * H_DIM;
    OW3[idx] = hi; OW3[idx + S] = mid; OW3[idx + 2 * S] = lo;
}

// ---------- x fp32 -> i8, coalesced both sides via LDS transpose (validated R12) ----------
__global__ void cvt_x_kernel(const float* __restrict__ x, int8_t* __restrict__ xb) {
    __shared__ int8_t sL[16384];
    const int chunk = blockIdx.x;                 // (t*32 + mIdx)*16 + kt
    const int kt   = chunk & 15;
    const int mIdx = (chunk >> 4) & 31;
    const int t    = chunk >> 9;
    const int tid  = threadIdx.x;
    const int wave = tid >> 6, lane = tid & 63;
    const int l31  = lane & 31;
    const int kk   = l31 >> 3, half = (l31 >> 2) & 1, j4 = (l31 & 3) * 4;
    const float* xrowbase = x + ((size_t)t * B_DIM + mIdx * 128) * I_DIM + kt * 128 + l31 * 4;
#pragma unroll
    for (int it = 0; it < 16; ++it) {
        const int r = wave * 32 + it * 2 + (lane >> 5);     // 0..127
        const int group = r >> 5, row32 = r & 31;
        float4 f = *(const float4*)(xrowbase + (size_t)r * I_DIM);
        uint32_t p = (uint32_t)(f.x > 0.5f)
                   | ((uint32_t)(f.y > 0.5f) << 8)
                   | ((uint32_t)(f.z > 0.5f) << 16)
                   | ((uint32_t)(f.w > 0.5f) << 24);
        *(uint32_t*)&sL[group * 4096 + kk * 1024 + (half * 32 + row32) * 16 + j4] = p;
    }
    __syncthreads();
    int4v* dst = (int4v*)xb + (size_t)chunk * 1024 + tid * 4;
    const int4v* srcv = (const int4v*)sL + tid * 4;
#pragma unroll
    for (int w = 0; w < 4; ++w) dst[w] = srcv[w];
}

// ---------- zero the group-sync counters ----------
__global__ void zero_cnt_kernel(uint32_t* __restrict__ cnt) {
    __hip_atomic_store(&cnt[blockIdx.x * 256 + threadIdx.x], 0u,
                       __ATOMIC_RELAXED, __HIP_MEMORY_SCOPE_AGENT);
}

// ====== R14: ONE barrier/iter, memory-model-correct ======
// R13 FAILED (absmax 0.285): vmcnt is PER-WAVE — draining iter i-1's staging after
// the top barrier lets wave W read segments whose producer (wave X) hasn't drained.
// Correct invariant: every producer drains its OWN staging (vmcnt 0) BEFORE the
// barrier that publishes the buffer to consumers. New body:
//   s_barrier                      // publishes cur (all waves drained at end of i-1)
//   stage nxt (10 ops)             // WAR-safe: nxt's readers (iter i-1) all finished
//                                  //   before they signaled this barrier
//   read cur + MFMA                // NO wait on the read path (cur pre-published)
//   lgkmcnt(0); vmcnt(0)           // own reads done + own staging drained -> may signal
// Staging still overlaps one full body (~2400cy > 900cy HBM). Waves drift across the
// whole body (only ONE alignment point): one wave's MFMA overlaps another's
// stage-issue/ds_reads -> LDS port and MFMA pipes co-busy (R12 showed them serialized:
// port 63% + MFMA 38% ~= 102%); setprio(1) (T5) now has a role-split to arbitrate.
// Phase contract: caller must STAGE buf0 and DRAIN OWN staging (vmcnt 0 per wave, or
// __syncthreads) before the phase's first barrier.
__device__ __forceinline__ void stage_a(const int8_t* __restrict__ aC, int8_t* dst,
                                        int wave, int lane) {
#pragma unroll
    for (int j = 0; j < 4; ++j) {
        const int seg = j * 4 + wave;
        gload_lds16(aC + (size_t)seg * 1024 + lane * 16, dst + seg * 1024);
    }
}
__device__ __forceinline__ void stage_b(const int8_t* __restrict__ bA,
                                        const int8_t* __restrict__ bB,
                                        int8_t* dst, int wave, int lane) {
    gload_lds16(bA + (size_t)wave * 1024 + lane * 16,       dst + wave * 1024);
    gload_lds16(bA + (size_t)(4 + wave) * 1024 + lane * 16, dst + (4 + wave) * 1024);
    gload_lds16(bA + (size_t)(8 + wave) * 1024 + lane * 16, dst + (8 + wave) * 1024);
    gload_lds16(bB + (size_t)wave * 1024 + lane * 16,       dst + 12288 + wave * 1024);
    gload_lds16(bB + (size_t)(4 + wave) * 1024 + lane * 16, dst + 12288 + (4 + wave) * 1024);
    gload_lds16(bB + (size_t)(8 + wave) * 1024 + lane * 16, dst + 12288 + (8 + wave) * 1024);
}

__device__ __forceinline__ void lif_iter(const int8_t* __restrict__ aCn,   // A(kt+1) chunk or null
                                         const int8_t* __restrict__ bAn,   // B(kt+1) strip0 or null
                                         const int8_t* __restrict__ bBn,   // B(kt+1) strip1 or null
                                         const int8_t* curA, const int8_t* curB,
                                         int8_t* nxtA, int8_t* nxtB,
                                         int wave, int lane, bool stage_next,
                                         int16v (&acc)[2][3]) {
    __builtin_amdgcn_s_barrier();              // publish cur; all iter i-1 reads complete
    __builtin_amdgcn_sched_barrier(0);
    if (stage_next) {
        stage_a(aCn, nxtA, wave, lane);
        stage_b(bAn, bBn, nxtB, wave, lane);
    }
    __builtin_amdgcn_sched_barrier(0);
    // wave (p = wave>>1, n = wave&1) owns rows [p*64, p*64+64) x strip n.
    // A-frag groups g = 2p+mf = (wave&~1)+mf; each bF feeds both mf MFMAs.
    const int gbase = wave & ~1;
    const int n = wave & 1;
    __builtin_amdgcn_s_setprio(1);             // T5: favor MFMA-phase waves during drift
#pragma unroll
    for (int kk = 0; kk < 4; ++kk) {
        int4v aF0 = *(const int4v*)(curA + gbase * 4096 + kk * 1024 + lane * 16);
        int4v aF1 = *(const int4v*)(curA + (gbase + 1) * 4096 + kk * 1024 + lane * 16);
#pragma unroll
        for (int s = 0; s < 3; ++s) {
            int4v bF = *(const int4v*)(curB + n * 12288 + s * 4096 + kk * 1024 + lane * 16);
            acc[0][s] = __builtin_amdgcn_mfma_i32_32x32x32_i8(aF0, bF, acc[0][s], 0, 0, 0);
            acc[1][s] = __builtin_amdgcn_mfma_i32_32x32x32_i8(aF1, bF, acc[1][s], 0, 0, 0);
        }
    }
    __builtin_amdgcn_s_setprio(0);
    asm volatile("s_waitcnt lgkmcnt(0)" ::: "memory");  // own LDS reads done
    asm volatile("s_waitcnt vmcnt(0)"  ::: "memory");   // own staging of nxt drained
                                                        // -> safe to signal next barrier
}

// Contract: caller has staged buf0 AND drained its own staging (vmcnt 0 per wave or a
// __syncthreads). NKT even: starts at buf0, last compute uses buf1, leaves buf0 free.
template<int NKT>
__device__ __forceinline__ void run_phase(const int8_t* __restrict__ aC,   // A chunk base, +kt*16384
                                          const int8_t* __restrict__ bA,   // strip0 base, +kt*12288
                                          const int8_t* __restrict__ bB,   // strip1 base, +kt*12288
                                          int8_t* sA0, int8_t* sA1, int8_t* sB0, int8_t* sB1,
                                          int wave, int lane, int16v (&acc)[2][3]) {
#pragma unroll 1
    for (int kt = 0; kt + 2 < NKT; kt += 2) {
        lif_iter(aC + (size_t)(kt + 1) * 16384, bA + (size_t)(kt + 1) * 12288,
                 bB + (size_t)(kt + 1) * 12288, sA0, sB0, sA1, sB1, wave, lane, true, acc);
        lif_iter(aC + (size_t)(kt + 2) * 16384, bA + (size_t)(kt + 2) * 12288,
                 bB + (size_t)(kt + 2) * 12288, sA1, sB1, sA0, sB0, wave, lane, true, acc);
    }
    lif_iter(aC + (size_t)(NKT - 1) * 16384, bA + (size_t)(NKT - 1) * 12288,
             bB + (size_t)(NKT - 1) * 12288, sA0, sB0, sA1, sB1, wave, lane, true, acc);
    lif_iter(nullptr, nullptr, nullptr, sA1, sB1, sA0, sB0, wave, lane, false, acc);
}

// ================= persistent LIF: all 14 steps, ONE PLAIN launch =================
// Tile 128M x 64N, grid 512, 2 blocks/CU: LDS 80KB x2 = 160KB exact, VGPR <= 256
// (launch_bounds 256,2 -> 8 waves/CU). mIdx group = 16 blocks (flag target 16).
// XCD grouping: mIdx = (bid&7)*4 + (q&3), nt2 = q>>2.
// Coherence protocol — validated R6..R12 through the timed path (no fences):
//  - dispatch boundaries invalidate L2s (replay staleness handled);
//  - ZS[t] virgin until producers' agent-scope 8B stores (LLC write-through,
//    vmcnt-acked before flag add); consumers spin + __syncthreads -> cached loads fresh;
//  - flag spin: relaxed agent-scope loads (no invalidates, groups drift freely).
__launch_bounds__(256, 2)
__global__ void lif_persist_kernel(const int8_t* __restrict__ Xall,
                                   const int8_t* __restrict__ WB,
                                   int8_t* __restrict__ ZS,      // 13 per-step z buffers
                                   uint16_t* __restrict__ Zbf,
                                   uint32_t* __restrict__ cnt) {
    __shared__ int8_t sMem[81920];
    int8_t* const sA0 = sMem;               // 16 KB
    int8_t* const sA1 = sMem + 16384;       // 16 KB (sZ aliases here during epilogue)
    int8_t* const sB0 = sMem + 32768;       // 24 KB
    int8_t* const sB1 = sMem + 57344;       // 24 KB
    int8_t* const sZ  = sA1;                // dead at epilogue time (ordering audited)

    const int tid  = threadIdx.x;
    const int wave = tid >> 6, lane = tid & 63;
    const int lane32 = lane & 31, hl = lane >> 5;

    // group-per-XCD swizzle: 512 blocks, 64 per XCD = 4 mIdx x 16 nt2
    const int bid = blockIdx.x;
    const int xs = bid & 7, q = bid >> 3;       // q in 0..63
    const int mIdx = xs * 4 + (q & 3);
    const int nt2  = q >> 2;                    // 0..15, covers nt = 2*nt2, 2*nt2+1

    const int mBase = mIdx * 128, nBase = nt2 * 64;
    const int8_t* wbA = WB + (size_t)(2 * nt2) * 24 * 12288;
    const int8_t* wbB = WB + (size_t)(2 * nt2 + 1) * 24 * 12288;

    // wave partition: p = row-half (64 rows), n = strip
    const int p = wave >> 1, n = wave & 1;

    float vmem[2][16], isyn[2][16];
#pragma unroll
    for (int mf = 0; mf < 2; ++mf)
#pragma unroll
        for (int r = 0; r < 16; ++r) { vmem[mf][r] = 0.0f; isyn[mf][r] = 0.0f; }

    // initial prologue: X(t=0) A(0) + B(0) -> buf0; drain OWN staging before iter0's
    // barrier (per the run_phase contract)
    stage_a(Xall + (size_t)mIdx * 16 * 16384, sA0, wave, lane);
    stage_b(wbA, wbB, sB0, wave, lane);
    asm volatile("s_waitcnt vmcnt(0)" ::: "memory");

    for (int t = 0; t < T_STEPS; ++t) {
        int16v acc[2][3] = {};   // [mf][digit]

        // ---- X phase: kt 0..15 (buf0 staged+drained per contract) ----
        const int8_t* XtC = Xall + (size_t)t * ((size_t)B_DIM * I_DIM)
                          + (size_t)mIdx * 16 * 16384;
        run_phase<16>(XtC, wbA, wbB, sA0, sA1, sB0, sB1, wave, lane, acc);

        // ---- recurrent phase: needs z(t-1) from the 16 blocks of this mIdx group ----
        if (t > 0) {
            const int8_t* zbA = wbA + (size_t)16 * 12288;
            const int8_t* zbB = wbB + (size_t)16 * 12288;
            // stage z-phase B(0) into sB0 (all sB0 reads finished before X-iter15's
            // top barrier; every wave has passed it on exiting run_phase)
            stage_b(zbA, zbB, sB0, wave, lane);
            if (tid == 0) {
                const uint32_t* f = cnt + ((size_t)mIdx * 13 + (t - 1)) * 32;
                while (__hip_atomic_load((uint32_t*)f, __ATOMIC_RELAXED, __HIP_MEMORY_SCOPE_AGENT) < 16u)
                    __builtin_amdgcn_s_sleep(2);
            }
            __syncthreads();   // spin visible; drains own stage_b (vmcnt 0 semantics)
            const int8_t* zC = ZS + (size_t)(t - 1) * ZBYTES + (size_t)mIdx * 8 * 16384;
            stage_a(zC, sA0, wave, lane);   // z A(0) (z data published by the spin)
            asm volatile("s_waitcnt vmcnt(0)" ::: "memory");   // drain own stage_a
            run_phase<8>(zC, zbA, zbB, sA0, sA1, sB0, sB1, wave, lane, acc);
        }

        // ---- step-boundary barrier: all waves' tail-iter LDS reads (incl. sA1) done
        //      before the epilogue writes sZ (= sA1) ----
        asm volatile("" ::: "memory");
        __builtin_amdgcn_s_barrier();
        __builtin_amdgcn_sched_barrier(0);

        // ---- prestage NEXT step's X A(0)/B(0) into buf0; latency hides under the
        //      epilogue; drained by the epilogue __syncthreads ----
        if (t + 1 < T_STEPS) {
            stage_a(Xall + (size_t)(t + 1) * ((size_t)B_DIM * I_DIM)
                    + (size_t)mIdx * 16 * 16384, sA0, wave, lane);
            stage_b(wbA, wbB, sB0, wave, lane);
        }

        // ---- LIF epilogue (registers): C/D row=(r&3)+8*(r>>2)+4*hl, col=lane32 ----
#pragma unroll
        for (int mf = 0; mf < 2; ++mf) {
#pragma unroll
            for (int r = 0; r < 16; ++r) {
#pragma clang fp contract(off)
                // exact digit combine (|counts| < 2^24)
                float cur = (float)acc[mf][2][r] * (1.0f / 512.0f)
                          + (float)acc[mf][1][r] * (1.0f / 131072.0f)
                          + (float)acc[mf][0][r] * (1.0f / 33554432.0f);
                int row = (r & 3) + 8 * (r >> 2) + 4 * hl;    // 0..31 (C/D layout)
                float v_dec = vmem[mf][r] + 0.1f * ((0.0f - vmem[mf][r]) + isyn[mf][r]);
                float i_dec = isyn[mf][r] - 0.2f * isyn[mf][r];
                bool z = (v_dec > 1.0f);
                vmem[mf][r] = z ? 0.0f : v_dec;               // == (1-z)*v_dec + z*V_RESET exactly
                isyn[mf][r] = i_dec + cur;
                if (t == T_STEPS - 1) {
                    int b = mBase + p * 64 + mf * 32 + row;
                    int h = nBase + n * 32 + lane32;
                    Zbf[(size_t)b * H_DIM + h] = z ? (uint16_t)0x3F80 : (uint16_t)0;
                } else {
                    // sZ[strip][group=2p+mf][lane'*16+j] — same layout as R10/R11
                    sZ[n * 4096 + ((wave & ~1) + mf) * 1024
                       + ((lane32 >> 4) * 32 + row) * 16 + (lane32 & 15)]
                        = z ? (int8_t)1 : (int8_t)0;
                }
            }
        }

        if (t < T_STEPS - 1) {
            __syncthreads();   // sZ complete; drains prestaged A/B (vmcnt 0)
            // repack: per strip, 16 contiguous bytes/thread -> two 8B agent-scope stores
#pragma unroll
            for (int ns = 0; ns < 2; ++ns) {
                const u64* sp = (const u64*)&sZ[ns * 4096 + tid * 16];
                u64 v0 = sp[0], v1 = sp[1];
                const int ntn = nt2 * 2 + ns;
                int8_t* dst = ZS + (size_t)t * ZBYTES + ((size_t)mIdx * 8 + (ntn >> 2)) * 16384
                            + (tid >> 6) * 4096 + (ntn & 3) * 1024 + (tid & 63) * 16;
                __hip_atomic_store((u64*)dst,       v0, __ATOMIC_RELAXED, __HIP_MEMORY_SCOPE_AGENT);
                __hip_atomic_store((u64*)(dst + 8), v1, __ATOMIC_RELAXED, __HIP_MEMORY_SCOPE_AGENT);
            }
            __syncthreads();   // all z-stores acked at the coherence point; sZ reads done
            if (tid == 0)
                __hip_atomic_fetch_add(&cnt[((size_t)mIdx * 13 + t) * 32], 1u,
                                       __ATOMIC_RELAXED, __HIP_MEMORY_SCOPE_AGENT);
        }
    }
}

// ---------- output GEMM: out = z_T @ out_w^T + out_b (bf16x3) ----------
__launch_bounds__(256)
__global__ void out_gemm_kernel(const uint16_t* __restrict__ Zfin,  // [B][H_DIM] bf16
                                const uint16_t* __restrict__ OW3,   // [3][O_DIM][H_DIM] bf16
                                const float* __restrict__ out_b,
                                float* __restrict__ out) {
    __shared__ uint16_t sA[16 * 32];        // 1 KB : [row(16)][k(32)]
    __shared__ uint16_t sB[3][128 * 32];    // 24 KB: [s][row(128)][k(32)]

    const int tid  = threadIdx.x;
    const int wave = tid >> 6, lane = tid & 63;
    const int quad = lane >> 4, col = lane & 15;

    const int mBase = blockIdx.x * 16;

    floatx4 acc[2] = {};

    const int ldRow = lane >> 2;        // 0..15
    const int ldCol = (lane & 3) * 8;   // element offset (x2B = 16B)

    for (int kt = 0; kt < H_DIM / 32; ++kt) {
        const int kb = kt * 32;
        __syncthreads();
        if (wave == 0) {
            const uint16_t* g = Zfin + (size_t)(mBase + ldRow) * H_DIM + kb + ldCol;
            gload_lds16(g, &sA[0]);
        }
#pragma unroll
        for (int s = 0; s < 3; ++s) {
            const uint16_t* wsrc = OW3 + (size_t)s * O_DIM * H_DIM;
#pragma unroll
            for (int j = 0; j < 2; ++j) {
                const int rseg = j * 4 + wave;   // 0..7, 16 rows each
                const uint16_t* g = wsrc + (size_t)(rseg * 16 + ldRow) * H_DIM + kb + ldCol;
                gload_lds16(g, &sB[s][rseg * 16 * 32]);
            }
        }
        __syncthreads();

        bf16x8 aF = *reinterpret_cast<const bf16x8*>(&sA[col * 32 + quad * 8]);
#pragma unroll
        for (int s = 0; s < 3; ++s) {
#pragma unroll
            for (int ni = 0; ni < 2; ++ni) {
                int row = wave * 32 + ni * 16 + col;
                bf16x8 bF = *reinterpret_cast<const bf16x8*>(&sB[s][row * 32 + quad * 8]);
                acc[ni] = __builtin_amdgcn_mfma_f32_16x16x32_bf16(aF, bF, acc[ni], 0, 0, 0);
            }
        }
    }

    {
#pragma clang fp contract(off)
#pragma unroll
        for (int ni = 0; ni < 2; ++ni)
#pragma unroll
            for (int r = 0; r < 4; ++r) {
                int b = mBase + quad * 4 + r;          // C/D: row = quad*4 + reg
                int h = wave * 32 + ni * 16 + col;     //      col = lane&15
                out[(size_t)b * O_DIM + h] = acc[ni][r] + out_b[h];
            }
    }
}

extern "C" void kernel_launch(void* const* d_in, const int* in_sizes, int n_in,
                              void* d_out, int out_size, void* d_ws, size_t ws_size,
                              hipStream_t stream) {
    const float* x     = (const float*)d_in[0];
    const float* w_in  = (const float*)d_in[1];
    const float* w_rec = (const float*)d_in[2];
    const float* out_w = (const float*)d_in[3];
    const float* out_b = (const float*)d_in[4];
    float* out = (float*)d_out;

    char* ws = (char*)d_ws;
    size_t off = 0;
    int8_t*   WB   = (int8_t*)(ws + off);   off += (size_t)3 * H_DIM * K_TOT;        // 9.4 MB
    uint16_t* OW3  = (uint16_t*)(ws + off); off += (size_t)3 * O_DIM * H_DIM * 2;    // 0.8 MB
    int8_t*   Xall = (int8_t*)(ws + off);   off += (size_t)T_STEPS * B_DIM * I_DIM;  // 117 MB
    uint16_t* Zbf  = (uint16_t*)(ws + off); off += (size_t)B_DIM * H_DIM * 2;        // 8 MB
    int8_t*   ZS   = (int8_t*)(ws + off);   off += (size_t)13 * ZBYTES;              // 54.5 MB (per-step z)
    uint32_t* CNT  = (uint32_t*)(ws + off); off += (size_t)32 * 13 * 32 * 4;         // 53 KB

    split_w_kernel<<<(H_DIM * K_TOT) / 256, 256, 0, stream>>>(w_in, w_rec, WB);
    split_ow_kernel<<<(O_DIM * H_DIM) / 256, 256, 0, stream>>>(out_w, OW3);
    cvt_x_kernel<<<T_STEPS * 32 * 16, 256, 0, stream>>>(x, Xall);
    zero_cnt_kernel<<<(32 * 13 * 32) / 256, 256, 0, stream>>>(CNT);

    // PLAIN launch: capture-safe. 512 blocks = 2/CU exact-fit (160KB LDS / 2 blocks).
    lif_persist_kernel<<<dim3(512), dim3(256), 0, stream>>>(Xall, WB, ZS, Zbf, CNT);

    out_gemm_kernel<<<B_DIM / 16, 256, 0, stream>>>(Zbf, OW3, out_b, out);
}